// Round 2
// baseline (1794.530 us; speedup 1.0000x reference)
//
#include <hip/hip_runtime.h>
#include <cstdint>
#include <cstddef>

// ---------------- problem constants ----------------
#define BB 8
#define SS 4096
#define DI 1024
#define DH 1024
#define MDIM (BB * SS)      // 32768
#define NC 128              // scan chunks per sequence
#define CL 32               // chunk length (NC*CL == SS)

// ---------------- ws layout (bytes) ----------------
static constexpr size_t OFF_XB   = 0;                         // 64MB
static constexpr size_t OFF_WZB  = 67108864;                  // 2MB
static constexpr size_t OFF_WHB  = OFF_WZB + 2097152;         // 2MB
static constexpr size_t OFF_K    = OFF_WHB + 2097152;         // 64MB fp16 gate preact k
static constexpr size_t OFF_P    = OFF_K + 67108864;          // 64MB fp16 candidate preact
static constexpr size_t OFF_CLA  = 0;                         // overlay (4MB) on dead xb
static constexpr size_t OFF_CLB  = 4194304;
static constexpr size_t OFF_CAR  = 8388608;
static constexpr size_t OFF_SYNC = 12582912;                  // 64B, zeroed post-GEMM

typedef __bf16 bf16;
typedef _Float16 fp16;
typedef short short8 __attribute__((ext_vector_type(8)));
typedef float f4 __attribute__((ext_vector_type(4)));
typedef float f32x8 __attribute__((ext_vector_type(8)));
typedef bf16 bf16x8 __attribute__((ext_vector_type(8)));
typedef fp16 h4 __attribute__((ext_vector_type(4)));

// ---------------- fp32 -> bf16 conversion ----------------
__global__ void convert_kernel(const float* __restrict__ x, const float* __restrict__ wz,
                               const float* __restrict__ wh,
                               bf16* __restrict__ xb, bf16* __restrict__ wzb, bf16* __restrict__ whb) {
    size_t i = ((size_t)blockIdx.x * 256 + threadIdx.x) * 8;
    const float* src; bf16* dst; size_t off;
    if (i < 33554432u) { src = x; dst = xb; off = i; }
    else if (i < 33554432u + 1048576u) { src = wz; dst = wzb; off = i - 33554432u; }
    else { src = wh; dst = whb; off = i - 34603008u; }
    f32x8 v = *(const f32x8*)(src + off);
    bf16x8 o = __builtin_convertvector(v, bf16x8);
    *(bf16x8*)(dst + off) = o;
}

// ---------------- async global->LDS (16B per lane) ----------------
__device__ __forceinline__ void gload_lds16(const void* g, void* l) {
    __builtin_amdgcn_global_load_lds((const __attribute__((address_space(1))) void*)g,
                                     (__attribute__((address_space(3))) void*)l, 16, 0, 0);
}

// raw barrier (no implicit vmcnt/lgkmcnt drain)
__device__ __forceinline__ void pbar() {
    asm volatile("" ::: "memory");
    __builtin_amdgcn_s_barrier();
    asm volatile("" ::: "memory");
}

// ================= 256x256 8-phase GEMM, persistent (4 tiles/block) =================
// LDS: 8 units of 16KB: buf d in [d*64K,+64K): A kh0@+0, A kh1@+16K, B kh0@+32K, B kh1@+48K.
// Unit: 256 rows x 32 bf16 (64B rows), st_16x32 swizzle (bank-conflict-free, measured 0).
__device__ __forceinline__ void stage_unit(const bf16* __restrict__ src, int row0, char* dst,
                                           int col0 /*elements*/, int w, int l) {
    const int cs = ((l & 3) ^ ((l >> 4) & 2)) << 4;   // pre-swizzled source col-byte
    const int r = row0 + w * 32 + (l >> 2);
    gload_lds16((const char*)(src + (size_t)r * DI + col0) + cs, dst + w * 2048 + l * 16);
    gload_lds16((const char*)(src + (size_t)(r + 16) * DI + col0) + cs, dst + w * 2048 + 1024 + l * 16);
}

__device__ __forceinline__ void read_a4(short8 (&af)[4], const char* base, int wr, int mf0, int l) {
    const char* p = base + (wr * 128 + mf0 * 16 + (l & 15)) * 64 + (((l >> 4) << 4) ^ ((l & 8) << 2));
#pragma unroll
    for (int i = 0; i < 4; i++) af[i] = *(const short8*)(p + i * 1024);
}

__device__ __forceinline__ void read_b4(short8 (&bf)[4], const char* base, int wc, int l) {
    const char* p = base + (wc * 64 + (l & 15)) * 64 + (((l >> 4) << 4) ^ ((l & 8) << 2));
#pragma unroll
    for (int j = 0; j < 4; j++) bf[j] = *(const short8*)(p + j * 1024);
}

template<int MF0>
__device__ __forceinline__ void mfma16(const short8 (&af)[4], const short8 (&bf)[4], f4 (&acc)[8][4]) {
    __builtin_amdgcn_s_setprio(1);          // T5
#pragma unroll
    for (int i = 0; i < 4; i++)
#pragma unroll
        for (int j = 0; j < 4; j++)
            acc[MF0 + i][j] = __builtin_amdgcn_mfma_f32_16x16x32_bf16(af[i], bf[j], acc[MF0 + i][j], 0, 0, 0);
    __builtin_amdgcn_s_setprio(0);
    asm volatile("s_waitcnt lgkmcnt(0)" ::: "memory");  // LDS region handoff safety
}

// Steady pair: 2 K-tiles, 8 phases; stages cur-tile k-tiles T+1(kh1),T+2,T+3(kh0).
// Valid for T=0..12 (T+3 <= 15). vmcnt(4) @P4/P8 only (counted, never 0 mid-loop).
__device__ __forceinline__ void ktile_steady(const bf16* __restrict__ A, const bf16* __restrict__ W,
                                             char* lds, int T, int m0, int n0,
                                             int w, int l, int wr, int wc, f4 (&acc)[8][4]) {
    short8 af[4], bf[4];
    // P1
    read_b4(bf, lds + 32768, wc, l);
    read_a4(af, lds + 0, wr, 0, l);
    stage_unit(A, m0, lds + 81920, (T + 1) * 64 + 32, w, l);
    pbar(); mfma16<0>(af, bf, acc); pbar();
    // P2
    read_a4(af, lds + 0, wr, 4, l);
    stage_unit(W, n0, lds + 114688, (T + 1) * 64 + 32, w, l);
    pbar(); mfma16<4>(af, bf, acc); pbar();
    // P3
    read_b4(bf, lds + 49152, wc, l);
    read_a4(af, lds + 16384, wr, 0, l);
    stage_unit(A, m0, lds + 0, (T + 2) * 64, w, l);
    pbar(); mfma16<0>(af, bf, acc); pbar();
    // P4
    read_a4(af, lds + 16384, wr, 4, l);
    stage_unit(W, n0, lds + 32768, (T + 2) * 64, w, l);
    asm volatile("s_waitcnt vmcnt(4)" ::: "memory");
    pbar(); mfma16<4>(af, bf, acc); pbar();
    // P5
    read_b4(bf, lds + 98304, wc, l);
    read_a4(af, lds + 65536, wr, 0, l);
    stage_unit(A, m0, lds + 16384, (T + 2) * 64 + 32, w, l);
    pbar(); mfma16<0>(af, bf, acc); pbar();
    // P6
    read_a4(af, lds + 65536, wr, 4, l);
    stage_unit(W, n0, lds + 49152, (T + 2) * 64 + 32, w, l);
    pbar(); mfma16<4>(af, bf, acc); pbar();
    // P7
    read_b4(bf, lds + 114688, wc, l);
    read_a4(af, lds + 81920, wr, 0, l);
    stage_unit(A, m0, lds + 65536, (T + 3) * 64, w, l);
    pbar(); mfma16<0>(af, bf, acc); pbar();
    // P8
    read_a4(af, lds + 81920, wr, 4, l);
    stage_unit(W, n0, lds + 98304, (T + 3) * 64, w, l);
    asm volatile("s_waitcnt vmcnt(4)" ::: "memory");
    pbar(); mfma16<4>(af, bf, acc); pbar();
}

// Boundary pair (T=14): P1/P2 stage cur k-tile 15 kh1 (col 992); P3-P8 stage the
// NEXT tile's k-tiles 0 (cols 0,32) and 1-kh0 (col 64) into the same LDS slots,
// so the next tile's first steady pair sees exactly the post-prologue state.
template<bool NEXT>
__device__ __forceinline__ void ktile_boundary(const bf16* __restrict__ A, const bf16* __restrict__ W,
                                               const bf16* __restrict__ An, const bf16* __restrict__ Wn,
                                               char* lds, int m0, int n0, int m0n, int n0n,
                                               int w, int l, int wr, int wc, f4 (&acc)[8][4]) {
    short8 af[4], bf[4];
    // P1
    read_b4(bf, lds + 32768, wc, l);
    read_a4(af, lds + 0, wr, 0, l);
    stage_unit(A, m0, lds + 81920, 992, w, l);
    pbar(); mfma16<0>(af, bf, acc); pbar();
    // P2
    read_a4(af, lds + 0, wr, 4, l);
    stage_unit(W, n0, lds + 114688, 992, w, l);
    pbar(); mfma16<4>(af, bf, acc); pbar();
    // P3
    read_b4(bf, lds + 49152, wc, l);
    read_a4(af, lds + 16384, wr, 0, l);
    if constexpr (NEXT) stage_unit(An, m0n, lds + 0, 0, w, l);
    pbar(); mfma16<0>(af, bf, acc); pbar();
    // P4
    read_a4(af, lds + 16384, wr, 4, l);
    if constexpr (NEXT) {
        stage_unit(Wn, n0n, lds + 32768, 0, w, l);
        asm volatile("s_waitcnt vmcnt(4)" ::: "memory");
    } else {
        asm volatile("s_waitcnt vmcnt(0)" ::: "memory");
    }
    pbar(); mfma16<4>(af, bf, acc); pbar();
    // P5
    read_b4(bf, lds + 98304, wc, l);
    read_a4(af, lds + 65536, wr, 0, l);
    if constexpr (NEXT) stage_unit(An, m0n, lds + 16384, 32, w, l);
    pbar(); mfma16<0>(af, bf, acc); pbar();
    // P6
    read_a4(af, lds + 65536, wr, 4, l);
    if constexpr (NEXT) stage_unit(Wn, n0n, lds + 49152, 32, w, l);
    pbar(); mfma16<4>(af, bf, acc); pbar();
    // P7
    read_b4(bf, lds + 114688, wc, l);
    read_a4(af, lds + 81920, wr, 0, l);
    if constexpr (NEXT) stage_unit(An, m0n, lds + 65536, 64, w, l);
    pbar(); mfma16<0>(af, bf, acc); pbar();
    // P8
    read_a4(af, lds + 81920, wr, 4, l);
    if constexpr (NEXT) {
        stage_unit(Wn, n0n, lds + 98304, 64, w, l);
        asm volatile("s_waitcnt vmcnt(4)" ::: "memory");
    } else {
        asm volatile("s_waitcnt vmcnt(0)" ::: "memory");
    }
    pbar(); mfma16<4>(af, bf, acc); pbar();
}

__device__ __forceinline__ void epi_store(f4 (&acc)[8][4], fp16* __restrict__ out,
                                          const float* __restrict__ bias,
                                          int m0, int n0, int wr, int wc, int l) {
    const int col16 = l & 15, quad = l >> 4;
#pragma unroll
    for (int nf = 0; nf < 4; nf++) {
        const int cg = n0 + wc * 64 + nf * 16 + col16;
        const float bv = bias[cg];
#pragma unroll
        for (int mf = 0; mf < 8; mf++) {
#pragma unroll
            for (int r = 0; r < 4; r++) {
                const int rg = m0 + wr * 128 + mf * 16 + quad * 4 + r;
                out[(size_t)rg * DH + cg] = (fp16)(acc[mf][nf][r] + bv);
            }
        }
    }
}

__global__ __launch_bounds__(512, 2)
void gemm256p(const bf16* __restrict__ A, const bf16* __restrict__ Wz, const bf16* __restrict__ Wh,
              const float* __restrict__ bz, const float* __restrict__ bh,
              fp16* __restrict__ kout, fp16* __restrict__ pout) {
    __shared__ __attribute__((aligned(16))) char lds[131072];
    const int t = threadIdx.x;
    const int l = t & 63, w = t >> 6;
    const int wr = w >> 2, wc = w & 3;
    const int xcd = blockIdx.x & 7, jj = blockIdx.x >> 3;

    // Tile tt of this block: widx = xcd*128 + tt*32 + jj — identical per-generation
    // XCD locality to the round-1 non-persistent mapping (measured FETCH ~98MB).
    const bf16* Wc; const float* bc; fp16* oc; int m0, n0;
    {
        int widx = xcd * 128 + jj;
        m0 = (widx >> 3) * 256;
        int g = (widx >> 2) & 1;
        Wc = g ? Wh : Wz; bc = g ? bh : bz; oc = g ? pout : kout;
        n0 = (widx & 3) * 256;
    }

    f4 acc[8][4];
#pragma unroll
    for (int i = 0; i < 8; i++)
#pragma unroll
        for (int j = 0; j < 4; j++) acc[i][j] = (f4)(0.f);

    // prologue: tile0 k-tiles 0 (full) + 1 (kh0); vmcnt(4) => first 4 units landed.
    stage_unit(A,  m0, lds + 0,     0,  w, l);
    stage_unit(Wc, n0, lds + 32768, 0,  w, l);
    stage_unit(A,  m0, lds + 16384, 32, w, l);
    stage_unit(Wc, n0, lds + 49152, 32, w, l);
    stage_unit(A,  m0, lds + 65536, 64, w, l);
    stage_unit(Wc, n0, lds + 98304, 64, w, l);
    asm volatile("s_waitcnt vmcnt(4)" ::: "memory");
    pbar();

#pragma unroll 1
    for (int tt = 0; tt < 4; ++tt) {
#pragma unroll 1
        for (int it = 0; it < 7; ++it)
            ktile_steady(A, Wc, lds, 2 * it, m0, n0, w, l, wr, wc, acc);

        const bf16* Wn = Wc; const float* bn = bc; fp16* on = oc; int m0n = m0, n0n = n0;
        if (tt < 3) {
            int widx = xcd * 128 + (tt + 1) * 32 + jj;
            m0n = (widx >> 3) * 256;
            int g = (widx >> 2) & 1;
            Wn = g ? Wh : Wz; bn = g ? bh : bz; on = g ? pout : kout;
            n0n = (widx & 3) * 256;
            ktile_boundary<true>(A, Wc, A, Wn, lds, m0, n0, m0n, n0n, w, l, wr, wc, acc);
        } else {
            ktile_boundary<false>(A, Wc, A, Wc, lds, m0, n0, m0, n0, w, l, wr, wc, acc);
        }

        // epilogue for tile tt: stores drain under next tile's P1-P3 (over-wait at
        // its P4 vmcnt(4) is correctness-safe; MFMA overwrites acc only after the
        // stores have consumed it, by register dependence).
        epi_store(acc, oc, bc, m0, n0, wr, wc, l);
#pragma unroll
        for (int i = 0; i < 8; i++)
#pragma unroll
            for (int j = 0; j < 4; j++) acc[i][j] = (f4)(0.f);

        Wc = Wn; bc = bn; oc = on; m0 = m0n; n0 = n0n;
    }
}

// ---------------- linear-space gates ----------------
__device__ __forceinline__ void gates_lin(float kv, float pv, float& a, float& b) {
    float ek = __expf(-kv);
    float z = __builtin_amdgcn_rcpf(1.f + ek);
    a = 1.f - z;
    float ep = __expf(-pv);
    float gneg = __builtin_amdgcn_rcpf(1.f + ep);
    float g = (pv >= 0.f) ? (pv + 0.5f) : gneg;
    b = z * g;
}

// ---------------- fused 3-phase scan with grid barrier ----------------
// 1024 blocks x 256 thr, no LDS, launch_bounds(256,4) caps VGPR<=128 ->
// 4 blocks/CU x 256 CUs = all 1024 co-resident (capacity 2048). Phase bodies are
// byte-identical to the previous 3 kernels (numerics unchanged).
__device__ __forceinline__ void gbar(unsigned* c) {
    __threadfence();
    __syncthreads();
    if (threadIdx.x == 0) {
        __hip_atomic_fetch_add(c, 1u, __ATOMIC_ACQ_REL, __HIP_MEMORY_SCOPE_AGENT);
        while (__hip_atomic_load(c, __ATOMIC_ACQUIRE, __HIP_MEMORY_SCOPE_AGENT) < 1024u)
            __builtin_amdgcn_s_sleep(8);
    }
    __syncthreads();
    __threadfence();
}

__global__ __launch_bounds__(256, 4)
void scan_fused(const fp16* __restrict__ kbuf, const fp16* __restrict__ pbuf,
                float* __restrict__ cla, float* __restrict__ clb,
                float* __restrict__ car, float* __restrict__ out,
                unsigned* __restrict__ sync) {
    const int tid = blockIdx.x * 256 + threadIdx.x;
    const int hq = tid & 255;
    const int c = (tid >> 8) & 127;
    const int b = tid >> 15;
    const size_t base = ((size_t)b * SS + (size_t)c * CL) * DH + hq * 4;
    const size_t ci = (size_t)(b * NC + c) * DH + hq * 4;

    // ---- phase 1: per-chunk affine composite ----
    {
        float A[4] = {1.f, 1.f, 1.f, 1.f};
        float Bc[4] = {0.f, 0.f, 0.f, 0.f};
#pragma unroll 4
        for (int tt = 0; tt < CL; tt++) {
            size_t idx = base + (size_t)tt * DH;
            h4 k4 = *(const h4*)(kbuf + idx);
            h4 p4 = *(const h4*)(pbuf + idx);
#pragma unroll
            for (int q = 0; q < 4; q++) {
                float a, bb;
                gates_lin((float)k4[q], (float)p4[q], a, bb);
                A[q] *= a;
                Bc[q] = fmaf(a, Bc[q], bb);
            }
        }
        *(f4*)(cla + ci) = *(f4*)A;
        *(f4*)(clb + ci) = *(f4*)Bc;
    }
    gbar(&sync[0]);

    // ---- phase 2: sequential scan over chunk summaries (first 32 blocks) ----
    if (blockIdx.x < 32) {
        const int b2 = tid >> 10;
        const int h2 = tid & 1023;
        float carry = 0.5f;
#pragma unroll 8
        for (int cc = 0; cc < NC; cc++) {
            const size_t c2 = (size_t)(b2 * NC + cc) * DH + h2;
            car[c2] = carry;
            carry = fmaf(cla[c2], carry, clb[c2]);
        }
    }
    gbar(&sync[16]);

    // ---- phase 3: apply within chunk, write h ----
    {
        f4 car4 = *(const f4*)(car + ci);
        float h[4] = {car4[0], car4[1], car4[2], car4[3]};
#pragma unroll 4
        for (int tt = 0; tt < CL; tt++) {
            size_t idx = base + (size_t)tt * DH;
            h4 k4 = *(const h4*)(kbuf + idx);
            h4 p4 = *(const h4*)(pbuf + idx);
            f4 o;
#pragma unroll
            for (int q = 0; q < 4; q++) {
                float a, bb;
                gates_lin((float)k4[q], (float)p4[q], a, bb);
                h[q] = fmaf(a, h[q], bb);
                o[q] = h[q];
            }
            *(f4*)(out + idx) = o;
        }
    }
}

// ---------------- launch ----------------
extern "C" void kernel_launch(void* const* d_in, const int* in_sizes, int n_in,
                              void* d_out, int out_size, void* d_ws, size_t ws_size,
                              hipStream_t stream) {
    const float* x  = (const float*)d_in[0];
    const float* Wz = (const float*)d_in[1];
    const float* bz = (const float*)d_in[2];
    const float* Wh = (const float*)d_in[3];
    const float* bh = (const float*)d_in[4];

    char* ws = (char*)d_ws;
    bf16* xb   = (bf16*)(ws + OFF_XB);
    bf16* wzb  = (bf16*)(ws + OFF_WZB);
    bf16* whb  = (bf16*)(ws + OFF_WHB);
    fp16* kbuf = (fp16*)(ws + OFF_K);
    fp16* pbuf = (fp16*)(ws + OFF_P);
    float* cla  = (float*)(ws + OFF_CLA);
    float* clb  = (float*)(ws + OFF_CLB);
    float* car  = (float*)(ws + OFF_CAR);
    unsigned* sync = (unsigned*)(ws + OFF_SYNC);
    float* out  = (float*)d_out;

    convert_kernel<<<17408, 256, 0, stream>>>(x, Wz, Wh, xb, wzb, whb);

    // persistent: 256 blocks x 4 tiles (both GEMMs)
    gemm256p<<<256, 512, 0, stream>>>(xb, wzb, whb, bz, bh, kbuf, pbuf);

    // zero barrier counters (region lies in dead xb space; must follow gemm)
    hipMemsetAsync(ws + OFF_SYNC, 0, 128, stream);

    scan_fused<<<1024, 256, 0, stream>>>(kbuf, pbuf, cla, clb, car, out, sync);
}

// Round 4
// 731.012 us; speedup vs baseline: 2.4549x; 2.4549x over previous
//
#include <hip/hip_runtime.h>
#include <cstdint>
#include <cstddef>

// ---------------- problem constants ----------------
#define BB 8
#define SS 4096
#define DI 1024
#define DH 1024
#define MDIM (BB * SS)      // 32768

// ---------------- ws layout (bytes) ----------------
static constexpr size_t OFF_XB   = 0;                         // 64MB
static constexpr size_t OFF_WZB  = 67108864;                  // 2MB
static constexpr size_t OFF_WHB  = OFF_WZB + 2097152;         // 2MB
static constexpr size_t OFF_K    = OFF_WHB + 2097152;         // 64MB fp16 gate preact k
static constexpr size_t OFF_P    = OFF_K + 67108864;          // 64MB fp16 candidate preact

typedef __bf16 bf16;
typedef _Float16 fp16;
typedef short short8 __attribute__((ext_vector_type(8)));
typedef float f4 __attribute__((ext_vector_type(4)));
typedef float f32x8 __attribute__((ext_vector_type(8)));
typedef bf16 bf16x8 __attribute__((ext_vector_type(8)));
typedef fp16 h4 __attribute__((ext_vector_type(4)));

// ---------------- fp32 -> bf16 conversion ----------------
__global__ void convert_kernel(const float* __restrict__ x, const float* __restrict__ wz,
                               const float* __restrict__ wh,
                               bf16* __restrict__ xb, bf16* __restrict__ wzb, bf16* __restrict__ whb) {
    size_t i = ((size_t)blockIdx.x * 256 + threadIdx.x) * 8;
    const float* src; bf16* dst; size_t off;
    if (i < 33554432u) { src = x; dst = xb; off = i; }
    else if (i < 33554432u + 1048576u) { src = wz; dst = wzb; off = i - 33554432u; }
    else { src = wh; dst = whb; off = i - 34603008u; }
    f32x8 v = *(const f32x8*)(src + off);
    bf16x8 o = __builtin_convertvector(v, bf16x8);
    *(bf16x8*)(dst + off) = o;
}

// ---------------- async global->LDS (16B per lane) ----------------
__device__ __forceinline__ void gload_lds16(const void* g, void* l) {
    __builtin_amdgcn_global_load_lds((const __attribute__((address_space(1))) void*)g,
                                     (__attribute__((address_space(3))) void*)l, 16, 0, 0);
}

// raw barrier (no implicit vmcnt/lgkmcnt drain)
__device__ __forceinline__ void pbar() {
    asm volatile("" ::: "memory");
    __builtin_amdgcn_s_barrier();
    asm volatile("" ::: "memory");
}

// ================= 256x256 8-phase GEMM (round-1 verbatim, 150us known-good) =================
// LDS: 8 units of 16KB: buf d in [d*64K, +64K): A kh0@+0, A kh1@+16K, B kh0@+32K, B kh1@+48K.
// Unit: 256 rows x 32 bf16 (64B rows), st_16x32 swizzle (measured 0 bank conflicts).
__device__ __forceinline__ void stage_unit(const bf16* __restrict__ src, int row0, char* dst,
                                           int col0 /*elements*/, int w, int l) {
    const int cs = ((l & 3) ^ ((l >> 4) & 2)) << 4;   // pre-swizzled source col-byte
    const int r = row0 + w * 32 + (l >> 2);
    gload_lds16((const char*)(src + (size_t)r * DI + col0) + cs, dst + w * 2048 + l * 16);
    gload_lds16((const char*)(src + (size_t)(r + 16) * DI + col0) + cs, dst + w * 2048 + 1024 + l * 16);
}

__device__ __forceinline__ void read_a4(short8 (&af)[4], const char* base, int wr, int mf0, int l) {
    const char* p = base + (wr * 128 + mf0 * 16 + (l & 15)) * 64 + (((l >> 4) << 4) ^ ((l & 8) << 2));
#pragma unroll
    for (int i = 0; i < 4; i++) af[i] = *(const short8*)(p + i * 1024);
}

__device__ __forceinline__ void read_b4(short8 (&bf)[4], const char* base, int wc, int l) {
    const char* p = base + (wc * 64 + (l & 15)) * 64 + (((l >> 4) << 4) ^ ((l & 8) << 2));
#pragma unroll
    for (int j = 0; j < 4; j++) bf[j] = *(const short8*)(p + j * 1024);
}

template<int MF0>
__device__ __forceinline__ void mfma16(const short8 (&af)[4], const short8 (&bf)[4], f4 (&acc)[8][4]) {
    __builtin_amdgcn_s_setprio(1);          // T5
#pragma unroll
    for (int i = 0; i < 4; i++)
#pragma unroll
        for (int j = 0; j < 4; j++)
            acc[MF0 + i][j] = __builtin_amdgcn_mfma_f32_16x16x32_bf16(af[i], bf[j], acc[MF0 + i][j], 0, 0, 0);
    __builtin_amdgcn_s_setprio(0);
    asm volatile("s_waitcnt lgkmcnt(0)" ::: "memory");  // LDS region handoff safety
}

// One iteration = 2 K-tiles (T even: buf0, T+1: buf1), 8 phases; counted vmcnt(4)
// only at P4/P8 (never 0 mid-loop).
template<bool FULL>
__device__ __forceinline__ void ktile_pair(const bf16* __restrict__ A, const bf16* __restrict__ W,
                                           char* lds, int T, int m0, int n0,
                                           int w, int l, int wr, int wc, f4 (&acc)[8][4]) {
    short8 af[4], bf[4];
    // P1
    read_b4(bf, lds + 32768, wc, l);
    read_a4(af, lds + 0, wr, 0, l);
    stage_unit(A, m0, lds + 81920, (T + 1) * 64 + 32, w, l);
    pbar(); mfma16<0>(af, bf, acc); pbar();
    // P2
    read_a4(af, lds + 0, wr, 4, l);
    stage_unit(W, n0, lds + 114688, (T + 1) * 64 + 32, w, l);
    pbar(); mfma16<4>(af, bf, acc); pbar();
    // P3
    read_b4(bf, lds + 49152, wc, l);
    read_a4(af, lds + 16384, wr, 0, l);
    if constexpr (FULL) stage_unit(A, m0, lds + 0, (T + 2) * 64, w, l);
    pbar(); mfma16<0>(af, bf, acc); pbar();
    // P4
    read_a4(af, lds + 16384, wr, 4, l);
    if constexpr (FULL) {
        stage_unit(W, n0, lds + 32768, (T + 2) * 64, w, l);
        asm volatile("s_waitcnt vmcnt(4)" ::: "memory");
    } else {
        asm volatile("s_waitcnt vmcnt(0)" ::: "memory");
    }
    pbar(); mfma16<4>(af, bf, acc); pbar();
    // P5
    read_b4(bf, lds + 98304, wc, l);
    read_a4(af, lds + 65536, wr, 0, l);
    if constexpr (FULL) stage_unit(A, m0, lds + 16384, (T + 2) * 64 + 32, w, l);
    pbar(); mfma16<0>(af, bf, acc); pbar();
    // P6
    read_a4(af, lds + 65536, wr, 4, l);
    if constexpr (FULL) stage_unit(W, n0, lds + 49152, (T + 2) * 64 + 32, w, l);
    pbar(); mfma16<4>(af, bf, acc); pbar();
    // P7
    read_b4(bf, lds + 114688, wc, l);
    read_a4(af, lds + 81920, wr, 0, l);
    if constexpr (FULL) stage_unit(A, m0, lds + 65536, (T + 3) * 64, w, l);
    pbar(); mfma16<0>(af, bf, acc); pbar();
    // P8
    read_a4(af, lds + 81920, wr, 4, l);
    if constexpr (FULL) {
        stage_unit(W, n0, lds + 98304, (T + 3) * 64, w, l);
        asm volatile("s_waitcnt vmcnt(4)" ::: "memory");
    } else {
        asm volatile("s_waitcnt vmcnt(0)" ::: "memory");
    }
    pbar(); mfma16<4>(af, bf, acc); pbar();
}

__global__ __launch_bounds__(512, 2)
void gemm256(const bf16* __restrict__ A, const bf16* __restrict__ Wz, const bf16* __restrict__ Wh,
             const float* __restrict__ bz, const float* __restrict__ bh,
             fp16* __restrict__ kout, fp16* __restrict__ pout) {
    __shared__ __attribute__((aligned(16))) char lds[131072];
    const int t = threadIdx.x;
    const int l = t & 63, w = t >> 6;
    const int wr = w >> 2, wc = w & 3;

    // XCD-bijective swizzle (1024 blocks, %8==0): each XCD owns disjoint m-tiles
    // (A fetched once into its L2) + both W matrices (4MB, L2-resident).
    const int bid = blockIdx.x;
    const int widx = (bid & 7) * 128 + (bid >> 3);
    const int m_idx = widx >> 3;
    const int gsel = (widx >> 2) & 1;
    const int n_idx = widx & 3;
    const bf16* W = gsel ? Wh : Wz;
    const float* bias = gsel ? bh : bz;
    fp16* out = gsel ? pout : kout;
    const int m0 = m_idx * 256, n0 = n_idx * 256;

    f4 acc[8][4];
#pragma unroll
    for (int i = 0; i < 8; i++)
#pragma unroll
        for (int j = 0; j < 4; j++) acc[i][j] = (f4)(0.f);

    // prologue: tile0 k-tiles 0 (full) + 1 (kh0); vmcnt(4) => first 4 units landed.
    stage_unit(A, m0, lds + 0,     0,  w, l);
    stage_unit(W, n0, lds + 32768, 0,  w, l);
    stage_unit(A, m0, lds + 16384, 32, w, l);
    stage_unit(W, n0, lds + 49152, 32, w, l);
    stage_unit(A, m0, lds + 65536, 64, w, l);
    stage_unit(W, n0, lds + 98304, 64, w, l);
    asm volatile("s_waitcnt vmcnt(4)" ::: "memory");
    pbar();

#pragma unroll 1
    for (int it = 0; it < 7; ++it)
        ktile_pair<true>(A, W, lds, 2 * it, m0, n0, w, l, wr, wc, acc);
    ktile_pair<false>(A, W, lds, 14, m0, n0, w, l, wr, wc, acc);

    // epilogue: bias add, fp16 store. C/D: col=lane&15, row=(lane>>4)*4+reg.
    const int col16 = l & 15, quad = l >> 4;
#pragma unroll
    for (int nf = 0; nf < 4; nf++) {
        const int cg = n0 + wc * 64 + nf * 16 + col16;
        const float bv = bias[cg];
#pragma unroll
        for (int mf = 0; mf < 8; mf++) {
#pragma unroll
            for (int r = 0; r < 4; r++) {
                const int rg = m0 + wr * 128 + mf * 16 + quad * 4 + r;
                out[(size_t)rg * DH + cg] = (fp16)(acc[mf][nf][r] + bv);
            }
        }
    }
}

// ---------------- linear-space gates ----------------
__device__ __forceinline__ void gates_lin(float kv, float pv, float& a, float& b) {
    float ek = __expf(-kv);
    float z = __builtin_amdgcn_rcpf(1.f + ek);     // sigmoid(k)
    a = 1.f - z;
    float ep = __expf(-pv);
    float gneg = __builtin_amdgcn_rcpf(1.f + ep);  // sigmoid(pre)
    float g = (pv >= 0.f) ? (pv + 0.5f) : gneg;
    b = z * g;
}

// ---------------- single-kernel block-local scan (no cross-block sync) ----------------
// block = (batch b, 8 h-columns). 256 threads = 128 c-threads x 2 h4-groups.
// c-thread owns timesteps [c*32, c*32+32). Phase A: serial affine composite.
// Phase B: 7-round Hillis-Steele over the 128 composites in LDS (affine compose
// is associative; double-buffered). Phase C: apply exclusive prefix, re-reading
// k/p (LLC-resident: 128MB < 256MB L3) and writing h.
__global__ __launch_bounds__(256, 4)
void scan_local(const fp16* __restrict__ kbuf, const fp16* __restrict__ pbuf,
                float* __restrict__ out) {
    __shared__ f4 sA[2][128][2];
    __shared__ f4 sB[2][128][2];
    const int b = blockIdx.x >> 7;
    const int h0 = (blockIdx.x & 127) * 8;
    const int c = threadIdx.x >> 1;
    const int g = threadIdx.x & 1;
    const size_t base = ((size_t)b * SS + (size_t)c * 32) * DH + h0 + g * 4;

    // ---- phase A: per-thread composite over its 32 steps ----
    f4 A = (f4)(1.f), Bc = (f4)(0.f);
#pragma unroll 8
    for (int t = 0; t < 32; t++) {
        size_t idx = base + (size_t)t * DH;
        h4 k4 = *(const h4*)(kbuf + idx);
        h4 p4 = *(const h4*)(pbuf + idx);
#pragma unroll
        for (int q = 0; q < 4; q++) {
            float a, bb;
            gates_lin((float)k4[q], (float)p4[q], a, bb);
            A[q] *= a;
            Bc[q] = fmaf(a, Bc[q], bb);
        }
    }

    // ---- phase B: inclusive scan over c ----
    sA[0][c][g] = A;
    sB[0][c][g] = Bc;
    __syncthreads();
    int cur = 0;
#pragma unroll
    for (int off = 1; off < 128; off <<= 1) {
        if (c >= off) {
            f4 pa = sA[cur][c - off][g];
            f4 pb = sB[cur][c - off][g];
#pragma unroll
            for (int q = 0; q < 4; q++) {
                Bc[q] = fmaf(A[q], pb[q], Bc[q]);
                A[q] *= pa[q];
            }
        }
        sA[cur ^ 1][c][g] = A;
        sB[cur ^ 1][c][g] = Bc;
        cur ^= 1;
        __syncthreads();
    }

    // carry-in for this thread's span = P_{c-1}(h0=0.5)
    f4 h;
    if (c == 0) {
        h = (f4)(0.5f);
    } else {
        f4 pa = sA[cur][c - 1][g];
        f4 pb = sB[cur][c - 1][g];
#pragma unroll
        for (int q = 0; q < 4; q++) h[q] = fmaf(pa[q], 0.5f, pb[q]);
    }

    // ---- phase C: re-read, apply recurrence, store ----
#pragma unroll 4
    for (int t = 0; t < 32; t++) {
        size_t idx = base + (size_t)t * DH;
        h4 k4 = *(const h4*)(kbuf + idx);
        h4 p4 = *(const h4*)(pbuf + idx);
        f4 o;
#pragma unroll
        for (int q = 0; q < 4; q++) {
            float a, bb;
            gates_lin((float)k4[q], (float)p4[q], a, bb);
            h[q] = fmaf(a, h[q], bb);
            o[q] = h[q];
        }
        *(f4*)(out + idx) = o;
    }
}

// ---------------- launch ----------------
extern "C" void kernel_launch(void* const* d_in, const int* in_sizes, int n_in,
                              void* d_out, int out_size, void* d_ws, size_t ws_size,
                              hipStream_t stream) {
    const float* x  = (const float*)d_in[0];
    const float* Wz = (const float*)d_in[1];
    const float* bz = (const float*)d_in[2];
    const float* Wh = (const float*)d_in[3];
    const float* bh = (const float*)d_in[4];

    char* ws = (char*)d_ws;
    bf16* xb   = (bf16*)(ws + OFF_XB);
    bf16* wzb  = (bf16*)(ws + OFF_WZB);
    bf16* whb  = (bf16*)(ws + OFF_WHB);
    fp16* kbuf = (fp16*)(ws + OFF_K);
    fp16* pbuf = (fp16*)(ws + OFF_P);
    float* out  = (float*)d_out;

    // 1) fp32 -> bf16
    convert_kernel<<<17408, 256, 0, stream>>>(x, Wz, Wh, xb, wzb, whb);

    // 2) both GEMMs: 128 m-tiles x 4 n-tiles x 2 = 1024 blocks of 512
    gemm256<<<1024, 512, 0, stream>>>(xb, wzb, whb, bz, bh, kbuf, pbuf);

    // 3) single block-local scan: 8 batches x 128 h-blocks = 1024 blocks
    scan_local<<<1024, 256, 0, stream>>>(kbuf, pbuf, out);
}

// Round 5
// 653.280 us; speedup vs baseline: 2.7470x; 1.1190x over previous
//
#include <hip/hip_runtime.h>
#include <cstdint>
#include <cstddef>

// ---------------- problem constants ----------------
#define BB 8
#define SS 4096
#define DI 1024
#define DH 1024
#define MDIM (BB * SS)      // 32768

// ---------------- ws layout (bytes) ----------------
static constexpr size_t OFF_XB   = 0;                         // 64MB
static constexpr size_t OFF_WZB  = 67108864;                  // 2MB
static constexpr size_t OFF_WHB  = OFF_WZB + 2097152;         // 2MB
static constexpr size_t OFF_K    = OFF_WHB + 2097152;         // 64MB fp16 k, TRANSPOSED [h][(b,s)]
static constexpr size_t OFF_P    = OFF_K + 67108864;          // 64MB fp16 pre, TRANSPOSED

typedef __bf16 bf16;
typedef _Float16 fp16;
typedef short short8 __attribute__((ext_vector_type(8)));
typedef float f4 __attribute__((ext_vector_type(4)));
typedef float f32x8 __attribute__((ext_vector_type(8)));
typedef bf16 bf16x8 __attribute__((ext_vector_type(8)));
typedef fp16 h4 __attribute__((ext_vector_type(4)));
typedef fp16 h8 __attribute__((ext_vector_type(8)));

// ---------------- fp32 -> bf16 conversion ----------------
__global__ void convert_kernel(const float* __restrict__ x, const float* __restrict__ wz,
                               const float* __restrict__ wh,
                               bf16* __restrict__ xb, bf16* __restrict__ wzb, bf16* __restrict__ whb) {
    size_t i = ((size_t)blockIdx.x * 256 + threadIdx.x) * 8;
    const float* src; bf16* dst; size_t off;
    if (i < 33554432u) { src = x; dst = xb; off = i; }
    else if (i < 33554432u + 1048576u) { src = wz; dst = wzb; off = i - 33554432u; }
    else { src = wh; dst = whb; off = i - 34603008u; }
    f32x8 v = *(const f32x8*)(src + off);
    bf16x8 o = __builtin_convertvector(v, bf16x8);
    *(bf16x8*)(dst + off) = o;
}

// ---------------- async global->LDS (16B per lane) ----------------
__device__ __forceinline__ void gload_lds16(const void* g, void* l) {
    __builtin_amdgcn_global_load_lds((const __attribute__((address_space(1))) void*)g,
                                     (__attribute__((address_space(3))) void*)l, 16, 0, 0);
}

// raw barrier (no implicit vmcnt/lgkmcnt drain)
__device__ __forceinline__ void pbar() {
    asm volatile("" ::: "memory");
    __builtin_amdgcn_s_barrier();
    asm volatile("" ::: "memory");
}

// ================= 256x256 8-phase GEMM (round-1 core, transposed epilogue) =================
// LDS: 8 units of 16KB: buf d in [d*64K, +64K): A kh0@+0, A kh1@+16K, B kh0@+32K, B kh1@+48K.
// Unit: 256 rows x 32 bf16 (64B rows), st_16x32 swizzle (measured 0 bank conflicts).
__device__ __forceinline__ void stage_unit(const bf16* __restrict__ src, int row0, char* dst,
                                           int col0 /*elements*/, int w, int l) {
    const int cs = ((l & 3) ^ ((l >> 4) & 2)) << 4;   // pre-swizzled source col-byte
    const int r = row0 + w * 32 + (l >> 2);
    gload_lds16((const char*)(src + (size_t)r * DI + col0) + cs, dst + w * 2048 + l * 16);
    gload_lds16((const char*)(src + (size_t)(r + 16) * DI + col0) + cs, dst + w * 2048 + 1024 + l * 16);
}

__device__ __forceinline__ void read_a4(short8 (&af)[4], const char* base, int wr, int mf0, int l) {
    const char* p = base + (wr * 128 + mf0 * 16 + (l & 15)) * 64 + (((l >> 4) << 4) ^ ((l & 8) << 2));
#pragma unroll
    for (int i = 0; i < 4; i++) af[i] = *(const short8*)(p + i * 1024);
}

__device__ __forceinline__ void read_b4(short8 (&bf)[4], const char* base, int wc, int l) {
    const char* p = base + (wc * 64 + (l & 15)) * 64 + (((l >> 4) << 4) ^ ((l & 8) << 2));
#pragma unroll
    for (int j = 0; j < 4; j++) bf[j] = *(const short8*)(p + j * 1024);
}

template<int MF0>
__device__ __forceinline__ void mfma16(const short8 (&af)[4], const short8 (&bf)[4], f4 (&acc)[8][4]) {
    __builtin_amdgcn_s_setprio(1);          // T5
#pragma unroll
    for (int i = 0; i < 4; i++)
#pragma unroll
        for (int j = 0; j < 4; j++)
            acc[MF0 + i][j] = __builtin_amdgcn_mfma_f32_16x16x32_bf16(af[i], bf[j], acc[MF0 + i][j], 0, 0, 0);
    __builtin_amdgcn_s_setprio(0);
    asm volatile("s_waitcnt lgkmcnt(0)" ::: "memory");  // LDS region handoff safety
}

// One iteration = 2 K-tiles (T even: buf0, T+1: buf1), 8 phases; counted vmcnt(4)
// only at P4/P8 (never 0 mid-loop).
template<bool FULL>
__device__ __forceinline__ void ktile_pair(const bf16* __restrict__ A, const bf16* __restrict__ W,
                                           char* lds, int T, int m0, int n0,
                                           int w, int l, int wr, int wc, f4 (&acc)[8][4]) {
    short8 af[4], bf[4];
    // P1
    read_b4(bf, lds + 32768, wc, l);
    read_a4(af, lds + 0, wr, 0, l);
    stage_unit(A, m0, lds + 81920, (T + 1) * 64 + 32, w, l);
    pbar(); mfma16<0>(af, bf, acc); pbar();
    // P2
    read_a4(af, lds + 0, wr, 4, l);
    stage_unit(W, n0, lds + 114688, (T + 1) * 64 + 32, w, l);
    pbar(); mfma16<4>(af, bf, acc); pbar();
    // P3
    read_b4(bf, lds + 49152, wc, l);
    read_a4(af, lds + 16384, wr, 0, l);
    if constexpr (FULL) stage_unit(A, m0, lds + 0, (T + 2) * 64, w, l);
    pbar(); mfma16<0>(af, bf, acc); pbar();
    // P4
    read_a4(af, lds + 16384, wr, 4, l);
    if constexpr (FULL) {
        stage_unit(W, n0, lds + 32768, (T + 2) * 64, w, l);
        asm volatile("s_waitcnt vmcnt(4)" ::: "memory");
    } else {
        asm volatile("s_waitcnt vmcnt(0)" ::: "memory");
    }
    pbar(); mfma16<4>(af, bf, acc); pbar();
    // P5
    read_b4(bf, lds + 98304, wc, l);
    read_a4(af, lds + 65536, wr, 0, l);
    if constexpr (FULL) stage_unit(A, m0, lds + 16384, (T + 2) * 64 + 32, w, l);
    pbar(); mfma16<0>(af, bf, acc); pbar();
    // P6
    read_a4(af, lds + 65536, wr, 4, l);
    if constexpr (FULL) stage_unit(W, n0, lds + 49152, (T + 2) * 64 + 32, w, l);
    pbar(); mfma16<4>(af, bf, acc); pbar();
    // P7
    read_b4(bf, lds + 114688, wc, l);
    read_a4(af, lds + 81920, wr, 0, l);
    if constexpr (FULL) stage_unit(A, m0, lds + 65536, (T + 3) * 64, w, l);
    pbar(); mfma16<0>(af, bf, acc); pbar();
    // P8
    read_a4(af, lds + 81920, wr, 4, l);
    if constexpr (FULL) {
        stage_unit(W, n0, lds + 98304, (T + 3) * 64, w, l);
        asm volatile("s_waitcnt vmcnt(4)" ::: "memory");
    } else {
        asm volatile("s_waitcnt vmcnt(0)" ::: "memory");
    }
    pbar(); mfma16<4>(af, bf, acc); pbar();
}

__global__ __launch_bounds__(512, 2)
void gemm256(const bf16* __restrict__ A, const bf16* __restrict__ Wz, const bf16* __restrict__ Wh,
             const float* __restrict__ bz, const float* __restrict__ bh,
             fp16* __restrict__ kout, fp16* __restrict__ pout) {
    __shared__ __attribute__((aligned(16))) char lds[131072];
    const int t = threadIdx.x;
    const int l = t & 63, w = t >> 6;
    const int wr = w >> 2, wc = w & 3;

    // XCD-bijective swizzle (1024 blocks, %8==0): each XCD owns disjoint m-tiles
    // (A fetched once into its L2) + both W matrices (4MB, L2-resident).
    const int bid = blockIdx.x;
    const int widx = (bid & 7) * 128 + (bid >> 3);
    const int m_idx = widx >> 3;
    const int gsel = (widx >> 2) & 1;
    const int n_idx = widx & 3;
    const bf16* W = gsel ? Wh : Wz;
    const float* bias = gsel ? bh : bz;
    fp16* out = gsel ? pout : kout;
    const int m0 = m_idx * 256, n0 = n_idx * 256;

    f4 acc[8][4];
#pragma unroll
    for (int i = 0; i < 8; i++)
#pragma unroll
        for (int j = 0; j < 4; j++) acc[i][j] = (f4)(0.f);

    // prologue: tile0 k-tiles 0 (full) + 1 (kh0); vmcnt(4) => first 4 units landed.
    stage_unit(A, m0, lds + 0,     0,  w, l);
    stage_unit(W, n0, lds + 32768, 0,  w, l);
    stage_unit(A, m0, lds + 16384, 32, w, l);
    stage_unit(W, n0, lds + 49152, 32, w, l);
    stage_unit(A, m0, lds + 65536, 64, w, l);
    stage_unit(W, n0, lds + 98304, 64, w, l);
    asm volatile("s_waitcnt vmcnt(4)" ::: "memory");
    pbar();

#pragma unroll 1
    for (int it = 0; it < 7; ++it)
        ktile_pair<true>(A, W, lds, 2 * it, m0, n0, w, l, wr, wc, acc);
    ktile_pair<false>(A, W, lds, 14, m0, n0, w, l, wr, wc, acc);

    // epilogue (TRANSPOSED): out[cg][rg], row length MDIM. acc r-index runs along
    // rg (row=(lane>>4)*4+r), so each (mf,nf) emits one h4 (8B) vector store.
    // Block covers rg in [m0,m0+256) for every cg it owns -> full-line coverage
    // -> L2/L3 write merge (measured: writes merge to ideal).
    const int col16 = l & 15, quad = l >> 4;
#pragma unroll
    for (int nf = 0; nf < 4; nf++) {
        const int cg = n0 + wc * 64 + nf * 16 + col16;
        const float bv = bias[cg];
#pragma unroll
        for (int mf = 0; mf < 8; mf++) {
            const int rg = m0 + wr * 128 + mf * 16 + quad * 4;
            h4 v;
#pragma unroll
            for (int r = 0; r < 4; r++) v[r] = (fp16)(acc[mf][nf][r] + bv);
            *(h4*)(out + (size_t)cg * MDIM + rg) = v;
        }
    }
}

// ---------------- linear-space gates ----------------
__device__ __forceinline__ void gates_lin(float kv, float pv, float& a, float& b) {
    float ek = __expf(-kv);
    float z = __builtin_amdgcn_rcpf(1.f + ek);     // sigmoid(k)
    a = 1.f - z;
    float ep = __expf(-pv);
    float gneg = __builtin_amdgcn_rcpf(1.f + ep);  // sigmoid(pre)
    float g = (pv >= 0.f) ? (pv + 0.5f) : gneg;
    b = z * g;
}

// ---------------- single-pass wave scan over transposed k/p ----------------
// wave = one (h, b) pair; lane l, chunk c owns s = c*512 + l*8 + {0..7}.
// Per chunk: 16B/lane fully-coalesced loads (1KB/instruction), gates held in
// registers (computed ONCE), per-lane 8-step fold -> 6-round shfl_up inclusive
// affine scan -> apply carry -> scalar stores (full-line coverage collectively;
// write merge measured ideal in round 4). No LDS, no syncthreads.
__global__ __launch_bounds__(512, 6)
void scan_wave(const fp16* __restrict__ kT, const fp16* __restrict__ pT,
               float* __restrict__ out) {
    const int t = threadIdx.x;
    const int l = t & 63;
    const int w = t >> 6;                   // 0..7
    const int b = blockIdx.x & 7;           // batch
    const int hg = blockIdx.x >> 3;         // 0..127
    const int h = hg * 8 + w;
    const size_t row = (size_t)h * MDIM + (size_t)b * SS;  // fp16 elements
    const fp16* kp = kT + row;
    const fp16* pp = pT + row;
    float* op = out + (size_t)b * SS * DH + h;             // out[(b*SS+s)*DH + h]

    float H = 0.5f;                          // running hidden state at chunk start
#pragma unroll 1
    for (int c = 0; c < 8; c++) {
        const int s0 = c * 512 + l * 8;
        h8 k8 = *(const h8*)(kp + s0);
        h8 p8 = *(const h8*)(pp + s0);
        float a[8], bb[8];
        float Ac = 1.f, Bc = 0.f;
#pragma unroll
        for (int q = 0; q < 8; q++) {
            gates_lin((float)k8[q], (float)p8[q], a[q], bb[q]);
            Ac *= a[q];
            Bc = fmaf(a[q], Bc, bb[q]);
        }
        // wave-inclusive scan of the 64 lane-segment composites (affine compose)
        float sa = Ac, sb = Bc;
#pragma unroll
        for (int off = 1; off < 64; off <<= 1) {
            float ta = __shfl_up(sa, off);
            float tb = __shfl_up(sb, off);
            if (l >= off) { sb = fmaf(sa, tb, sb); sa *= ta; }
        }
        // carry-in for this lane = exclusive prefix applied to H
        float pa = __shfl_up(sa, 1);
        float pb = __shfl_up(sb, 1);
        float hv = (l == 0) ? H : fmaf(pa, H, pb);
        // chunk total (lane 63 inclusive) advances H
        float ga = __shfl(sa, 63);
        float gb = __shfl(sb, 63);
        H = fmaf(ga, H, gb);
        // apply recurrence over this lane's 8 steps, store
#pragma unroll
        for (int q = 0; q < 8; q++) {
            hv = fmaf(a[q], hv, bb[q]);
            op[(size_t)(s0 + q) * DH] = hv;
        }
    }
}

// ---------------- launch ----------------
extern "C" void kernel_launch(void* const* d_in, const int* in_sizes, int n_in,
                              void* d_out, int out_size, void* d_ws, size_t ws_size,
                              hipStream_t stream) {
    const float* x  = (const float*)d_in[0];
    const float* Wz = (const float*)d_in[1];
    const float* bz = (const float*)d_in[2];
    const float* Wh = (const float*)d_in[3];
    const float* bh = (const float*)d_in[4];

    char* ws = (char*)d_ws;
    bf16* xb   = (bf16*)(ws + OFF_XB);
    bf16* wzb  = (bf16*)(ws + OFF_WZB);
    bf16* whb  = (bf16*)(ws + OFF_WHB);
    fp16* kbuf = (fp16*)(ws + OFF_K);    // transposed [h][(b,s)]
    fp16* pbuf = (fp16*)(ws + OFF_P);    // transposed
    float* out  = (float*)d_out;

    // 1) fp32 -> bf16
    convert_kernel<<<17408, 256, 0, stream>>>(x, Wz, Wh, xb, wzb, whb);

    // 2) both GEMMs: 128 m-tiles x 4 n-tiles x 2 = 1024 blocks of 512
    gemm256<<<1024, 512, 0, stream>>>(xb, wzb, whb, bz, bh, kbuf, pbuf);

    // 3) single-pass wave scan: 8 b x 128 h-groups = 1024 blocks of 512
    scan_wave<<<1024, 512, 0, stream>>>(kbuf, pbuf, out);
}

// Round 7
// 471.716 us; speedup vs baseline: 3.8043x; 1.3849x over previous
//
#include <hip/hip_runtime.h>
#include <cstdint>
#include <cstddef>

// ---------------- problem constants ----------------
#define BB 8
#define SS 4096
#define DI 1024
#define DH 1024
#define MDIM (BB * SS)      // 32768

// ---------------- ws layout (bytes) ----------------
static constexpr size_t OFF_XB   = 0;                         // 64MB
static constexpr size_t OFF_WZB  = 67108864;                  // 2MB
static constexpr size_t OFF_WHB  = OFF_WZB + 2097152;         // 2MB
static constexpr size_t OFF_K    = OFF_WHB + 2097152;         // 64MB fp16 k, TRANSPOSED [h][(b,s)]
static constexpr size_t OFF_P    = OFF_K + 67108864;          // 64MB fp16 pre, TRANSPOSED

typedef __bf16 bf16;
typedef _Float16 fp16;
typedef short short8 __attribute__((ext_vector_type(8)));
typedef float f4 __attribute__((ext_vector_type(4)));
typedef float f32x8 __attribute__((ext_vector_type(8)));
typedef bf16 bf16x8 __attribute__((ext_vector_type(8)));
typedef fp16 h4 __attribute__((ext_vector_type(4)));
typedef fp16 h8 __attribute__((ext_vector_type(8)));

// ---------------- fp32 -> bf16 conversion ----------------
__global__ void convert_kernel(const float* __restrict__ x, const float* __restrict__ wz,
                               const float* __restrict__ wh,
                               bf16* __restrict__ xb, bf16* __restrict__ wzb, bf16* __restrict__ whb) {
    size_t i = ((size_t)blockIdx.x * 256 + threadIdx.x) * 8;
    const float* src; bf16* dst; size_t off;
    if (i < 33554432u) { src = x; dst = xb; off = i; }
    else if (i < 33554432u + 1048576u) { src = wz; dst = wzb; off = i - 33554432u; }
    else { src = wh; dst = whb; off = i - 34603008u; }
    f32x8 v = *(const f32x8*)(src + off);
    bf16x8 o = __builtin_convertvector(v, bf16x8);
    *(bf16x8*)(dst + off) = o;
}

// ---------------- async global->LDS (16B per lane) ----------------
__device__ __forceinline__ void gload_lds16(const void* g, void* l) {
    __builtin_amdgcn_global_load_lds((const __attribute__((address_space(1))) void*)g,
                                     (__attribute__((address_space(3))) void*)l, 16, 0, 0);
}

// raw barrier (no implicit vmcnt/lgkmcnt drain)
__device__ __forceinline__ void pbar() {
    asm volatile("" ::: "memory");
    __builtin_amdgcn_s_barrier();
    asm volatile("" ::: "memory");
}

// ================= 256x256 8-phase GEMM (round-1 core, transposed epilogue) =================
// LDS: 8 units of 16KB: buf d in [d*64K, +64K): A kh0@+0, A kh1@+16K, B kh0@+32K, B kh1@+48K.
// Unit: 256 rows x 32 bf16 (64B rows), st_16x32 swizzle (measured 0 bank conflicts).
__device__ __forceinline__ void stage_unit(const bf16* __restrict__ src, int row0, char* dst,
                                           int col0 /*elements*/, int w, int l) {
    const int cs = ((l & 3) ^ ((l >> 4) & 2)) << 4;   // pre-swizzled source col-byte
    const int r = row0 + w * 32 + (l >> 2);
    gload_lds16((const char*)(src + (size_t)r * DI + col0) + cs, dst + w * 2048 + l * 16);
    gload_lds16((const char*)(src + (size_t)(r + 16) * DI + col0) + cs, dst + w * 2048 + 1024 + l * 16);
}

__device__ __forceinline__ void read_a4(short8 (&af)[4], const char* base, int wr, int mf0, int l) {
    const char* p = base + (wr * 128 + mf0 * 16 + (l & 15)) * 64 + (((l >> 4) << 4) ^ ((l & 8) << 2));
#pragma unroll
    for (int i = 0; i < 4; i++) af[i] = *(const short8*)(p + i * 1024);
}

__device__ __forceinline__ void read_b4(short8 (&bf)[4], const char* base, int wc, int l) {
    const char* p = base + (wc * 64 + (l & 15)) * 64 + (((l >> 4) << 4) ^ ((l & 8) << 2));
#pragma unroll
    for (int j = 0; j < 4; j++) bf[j] = *(const short8*)(p + j * 1024);
}

template<int MF0>
__device__ __forceinline__ void mfma16(const short8 (&af)[4], const short8 (&bf)[4], f4 (&acc)[8][4]) {
    __builtin_amdgcn_s_setprio(1);          // T5
#pragma unroll
    for (int i = 0; i < 4; i++)
#pragma unroll
        for (int j = 0; j < 4; j++)
            acc[MF0 + i][j] = __builtin_amdgcn_mfma_f32_16x16x32_bf16(af[i], bf[j], acc[MF0 + i][j], 0, 0, 0);
    __builtin_amdgcn_s_setprio(0);
    asm volatile("s_waitcnt lgkmcnt(0)" ::: "memory");  // LDS region handoff safety
}

// One iteration = 2 K-tiles (T even: buf0, T+1: buf1), 8 phases; counted vmcnt(4)
// only at P4/P8 (never 0 mid-loop).
template<bool FULL>
__device__ __forceinline__ void ktile_pair(const bf16* __restrict__ A, const bf16* __restrict__ W,
                                           char* lds, int T, int m0, int n0,
                                           int w, int l, int wr, int wc, f4 (&acc)[8][4]) {
    short8 af[4], bf[4];
    // P1
    read_b4(bf, lds + 32768, wc, l);
    read_a4(af, lds + 0, wr, 0, l);
    stage_unit(A, m0, lds + 81920, (T + 1) * 64 + 32, w, l);
    pbar(); mfma16<0>(af, bf, acc); pbar();
    // P2
    read_a4(af, lds + 0, wr, 4, l);
    stage_unit(W, n0, lds + 114688, (T + 1) * 64 + 32, w, l);
    pbar(); mfma16<4>(af, bf, acc); pbar();
    // P3
    read_b4(bf, lds + 49152, wc, l);
    read_a4(af, lds + 16384, wr, 0, l);
    if constexpr (FULL) stage_unit(A, m0, lds + 0, (T + 2) * 64, w, l);
    pbar(); mfma16<0>(af, bf, acc); pbar();
    // P4
    read_a4(af, lds + 16384, wr, 4, l);
    if constexpr (FULL) {
        stage_unit(W, n0, lds + 32768, (T + 2) * 64, w, l);
        asm volatile("s_waitcnt vmcnt(4)" ::: "memory");
    } else {
        asm volatile("s_waitcnt vmcnt(0)" ::: "memory");
    }
    pbar(); mfma16<4>(af, bf, acc); pbar();
    // P5
    read_b4(bf, lds + 98304, wc, l);
    read_a4(af, lds + 65536, wr, 0, l);
    if constexpr (FULL) stage_unit(A, m0, lds + 16384, (T + 2) * 64 + 32, w, l);
    pbar(); mfma16<0>(af, bf, acc); pbar();
    // P6
    read_a4(af, lds + 65536, wr, 4, l);
    if constexpr (FULL) stage_unit(W, n0, lds + 49152, (T + 2) * 64 + 32, w, l);
    pbar(); mfma16<4>(af, bf, acc); pbar();
    // P7
    read_b4(bf, lds + 114688, wc, l);
    read_a4(af, lds + 81920, wr, 0, l);
    if constexpr (FULL) stage_unit(A, m0, lds + 65536, (T + 3) * 64, w, l);
    pbar(); mfma16<0>(af, bf, acc); pbar();
    // P8
    read_a4(af, lds + 81920, wr, 4, l);
    if constexpr (FULL) {
        stage_unit(W, n0, lds + 98304, (T + 3) * 64, w, l);
        asm volatile("s_waitcnt vmcnt(4)" ::: "memory");
    } else {
        asm volatile("s_waitcnt vmcnt(0)" ::: "memory");
    }
    pbar(); mfma16<4>(af, bf, acc); pbar();
}

__global__ __launch_bounds__(512, 2)
void gemm256(const bf16* __restrict__ A, const bf16* __restrict__ Wz, const bf16* __restrict__ Wh,
             const float* __restrict__ bz, const float* __restrict__ bh,
             fp16* __restrict__ kout, fp16* __restrict__ pout) {
    __shared__ __attribute__((aligned(16))) char lds[131072];
    const int t = threadIdx.x;
    const int l = t & 63, w = t >> 6;
    const int wr = w >> 2, wc = w & 3;

    // XCD-bijective swizzle (1024 blocks, %8==0): each XCD owns disjoint m-tiles
    // (A fetched once into its L2) + both W matrices (4MB, L2-resident).
    const int bid = blockIdx.x;
    const int widx = (bid & 7) * 128 + (bid >> 3);
    const int m_idx = widx >> 3;
    const int gsel = (widx >> 2) & 1;
    const int n_idx = widx & 3;
    const bf16* W = gsel ? Wh : Wz;
    const float* bias = gsel ? bh : bz;
    fp16* out = gsel ? pout : kout;
    const int m0 = m_idx * 256, n0 = n_idx * 256;

    f4 acc[8][4];
#pragma unroll
    for (int i = 0; i < 8; i++)
#pragma unroll
        for (int j = 0; j < 4; j++) acc[i][j] = (f4)(0.f);

    // prologue: tile0 k-tiles 0 (full) + 1 (kh0); vmcnt(4) => first 4 units landed.
    stage_unit(A, m0, lds + 0,     0,  w, l);
    stage_unit(W, n0, lds + 32768, 0,  w, l);
    stage_unit(A, m0, lds + 16384, 32, w, l);
    stage_unit(W, n0, lds + 49152, 32, w, l);
    stage_unit(A, m0, lds + 65536, 64, w, l);
    stage_unit(W, n0, lds + 98304, 64, w, l);
    asm volatile("s_waitcnt vmcnt(4)" ::: "memory");
    pbar();

#pragma unroll 1
    for (int it = 0; it < 7; ++it)
        ktile_pair<true>(A, W, lds, 2 * it, m0, n0, w, l, wr, wc, acc);
    ktile_pair<false>(A, W, lds, 14, m0, n0, w, l, wr, wc, acc);

    // epilogue (TRANSPOSED): out[cg][rg], row length MDIM. acc r-index runs along
    // rg, so each (mf,nf) emits one h4 (8B) vector store; lanes {l,l+16,l+32,l+48}
    // cover 32B contiguous rg per instruction -> sector-atomic -> writes merge.
    const int col16 = l & 15, quad = l >> 4;
#pragma unroll
    for (int nf = 0; nf < 4; nf++) {
        const int cg = n0 + wc * 64 + nf * 16 + col16;
        const float bv = bias[cg];
#pragma unroll
        for (int mf = 0; mf < 8; mf++) {
            const int rg = m0 + wr * 128 + mf * 16 + quad * 4;
            h4 v;
#pragma unroll
            for (int r = 0; r < 4; r++) v[r] = (fp16)(acc[mf][nf][r] + bv);
            *(h4*)(out + (size_t)cg * MDIM + rg) = v;
        }
    }
}

// ---------------- linear-space gates ----------------
__device__ __forceinline__ void gates_lin(float kv, float pv, float& a, float& b) {
    float ek = __expf(-kv);
    float z = __builtin_amdgcn_rcpf(1.f + ek);     // sigmoid(k)
    a = 1.f - z;
    float ep = __expf(-pv);
    float gneg = __builtin_amdgcn_rcpf(1.f + ep);  // sigmoid(pre)
    float g = (pv >= 0.f) ? (pv + 0.5f) : gneg;
    b = z * g;
}

// ---------------- wave scan over transposed k/p, LDS-turned sector-atomic stores ----------------
// wave = one (h, b); lane l, chunk c owns s = c*512 + l*8 + {0..7}. Loads 16B/lane
// coalesced; gates computed once in registers; 6-round shfl_up affine scan
// (verified round 5). NEW: results go through a [8 h][512 s] LDS tile per chunk;
// then each thread emits ONE 32B contiguous store out[(b*SS+s)*DH + h0..h0+8)
// (single-lane sector-atomic -> ideal write merge, the round-4-measured pattern).
__global__ __launch_bounds__(512, 8)
void scan_wave(const fp16* __restrict__ kT, const fp16* __restrict__ pT,
               float* __restrict__ out) {
    __shared__ float tile[8][512];          // 16KB
    const int t = threadIdx.x;
    const int l = t & 63;
    const int w = t >> 6;                   // 0..7 -> h offset within group
    const int b = blockIdx.x & 7;           // batch
    const int hg = blockIdx.x >> 3;         // 0..127
    const int h = hg * 8 + w;
    const size_t row = (size_t)h * MDIM + (size_t)b * SS;  // fp16 elements
    const fp16* kp = kT + row;
    const fp16* pp = pT + row;
    float* op = out + ((size_t)b * SS) * DH + hg * 8;      // + s*DH + (0..7)

    float H = 0.5f;                          // running hidden state at chunk start
#pragma unroll 1
    for (int c = 0; c < 8; c++) {
        const int s0 = c * 512 + l * 8;
        h8 k8 = *(const h8*)(kp + s0);
        h8 p8 = *(const h8*)(pp + s0);
        float a[8], bb[8];
        float Ac = 1.f, Bc = 0.f;
#pragma unroll
        for (int q = 0; q < 8; q++) {
            gates_lin((float)k8[q], (float)p8[q], a[q], bb[q]);
            Ac *= a[q];
            Bc = fmaf(a[q], Bc, bb[q]);
        }
        // wave-inclusive scan of the 64 lane-segment composites (affine compose)
        float sa = Ac, sb = Bc;
#pragma unroll
        for (int off = 1; off < 64; off <<= 1) {
            float ta = __shfl_up(sa, off);
            float tb = __shfl_up(sb, off);
            if (l >= off) { sb = fmaf(sa, tb, sb); sa *= ta; }
        }
        // carry-in for this lane = exclusive prefix applied to H
        float pa = __shfl_up(sa, 1);
        float pb = __shfl_up(sb, 1);
        float hv = (l == 0) ? H : fmaf(pa, H, pb);
        // chunk total (lane 63 inclusive) advances H
        float ga = __shfl(sa, 63);
        float gb = __shfl(sb, 63);
        H = fmaf(ga, H, gb);
        // apply recurrence over this lane's 8 steps into registers
        float o[8];
#pragma unroll
        for (int q = 0; q < 8; q++) {
            hv = fmaf(a[q], hv, bb[q]);
            o[q] = hv;
        }
        // LDS turn: wave w writes its h-row, s_local = l*8..+8 (2x b128)
        *(f4*)(&tile[w][l * 8])     = *(f4*)(&o[0]);
        *(f4*)(&tile[w][l * 8 + 4]) = *(f4*)(&o[4]);
        __syncthreads();
        // cooperative store: thread t owns s_local = t; 8 scalar ds_reads
        // (2 lanes/bank = free), one 32B contiguous global store.
        float v[8];
#pragma unroll
        for (int i = 0; i < 8; i++) v[i] = tile[i][t];
        float* od = op + (size_t)(c * 512 + t) * DH;
        *(f4*)(od)     = *(f4*)(&v[0]);
        *(f4*)(od + 4) = *(f4*)(&v[4]);
        __syncthreads();   // protect tile before next chunk overwrites
    }
}

// ---------------- launch ----------------
extern "C" void kernel_launch(void* const* d_in, const int* in_sizes, int n_in,
                              void* d_out, int out_size, void* d_ws, size_t ws_size,
                              hipStream_t stream) {
    const float* x  = (const float*)d_in[0];
    const float* Wz = (const float*)d_in[1];
    const float* bz = (const float*)d_in[2];
    const float* Wh = (const float*)d_in[3];
    const float* bh = (const float*)d_in[4];

    char* ws = (char*)d_ws;
    bf16* xb   = (bf16*)(ws + OFF_XB);
    bf16* wzb  = (bf16*)(ws + OFF_WZB);
    bf16* whb  = (bf16*)(ws + OFF_WHB);
    fp16* kbuf = (fp16*)(ws + OFF_K);    // transposed [h][(b,s)]
    fp16* pbuf = (fp16*)(ws + OFF_P);    // transposed
    float* out  = (float*)d_out;

    // 1) fp32 -> bf16
    convert_kernel<<<17408, 256, 0, stream>>>(x, Wz, Wh, xb, wzb, whb);

    // 2) both GEMMs: 128 m-tiles x 4 n-tiles x 2 = 1024 blocks of 512
    gemm256<<<1024, 512, 0, stream>>>(xb, wzb, whb, bz, bh, kbuf, pbuf);

    // 3) wave scan with LDS-turned stores: 8 b x 128 h-groups = 1024 blocks
    scan_wave<<<1024, 512, 0, stream>>>(kbuf, pbuf, out);
}